// Round 5
// baseline (81301.532 us; speedup 1.0000x reference)
//
#include <hip/hip_runtime.h>
#include <stdint.h>

// ---------------------------------------------------------------------------
// Tacotron2-style decoder, 400 sequential steps. R5: kernel-boundary sync.
//   R1-R4 post-mortem: persistent kernel + software grid barrier gives a
//   ~30-45us/phase floor that resists payload/barrier/coherence changes.
//   R5 replaces the barrier substrate: 2 kernels per step in the captured
//   graph (k_m: both LSTM gate GEMMs + cells + conv; k_s: attention scalar
//   chain + proj). All memory ops are normal cached loads/stores; coherence
//   comes from dispatch boundaries. No atomics, no flags, no agent-scope ops.
// Per step: k_m (256 blocks x 512): dec-gates(t-1)+dec-cell -> DH;
//                                   att-gates(t)+att-cell -> AC;
//                                   loc-conv+loc-proj -> SBUF.
//           k_s (32 blocks x 512):  q = qW@ac; energies (LDS); softmax;
//                                   ctx; proj(t-1) -> mel/gate outputs.
// Tail: k_m(t=400, dec only) + k_proj(399).
// ---------------------------------------------------------------------------

#define NB  32
#define TI  512
#define ED  576
#define TO  400
#define NM  80
#define PR  256
#define AR  1024
#define DR  1024
#define AD  128
#define NFl 32
#define KSz 31
#define KA  1856
#define KD  2624
#define NKT_A 58
#define NKT_D 82

typedef __attribute__((ext_vector_type(8))) short bf8_t;
typedef __attribute__((ext_vector_type(4))) float f4_t;
typedef __attribute__((ext_vector_type(2))) float f2_t;

__device__ __forceinline__ short f2bf(float f){
  union { float f; unsigned u; } v; v.f = f;
  unsigned r = v.u + 0x7fffu + ((v.u >> 16) & 1u);
  return (short)(r >> 16);
}
__device__ __forceinline__ float bf2f(short s){
  union { unsigned u; float f; } v; v.u = ((unsigned)(unsigned short)s) << 16; return v.f;
}
__device__ __forceinline__ float sigm(float x){ return 1.f / (1.f + __expf(-x)); }

__device__ __forceinline__ f4_t MFMA(bf8_t a, bf8_t b, f4_t c){
  return __builtin_amdgcn_mfma_f32_16x16x32_bf16(a, b, c, 0, 0, 0);
}

__device__ __forceinline__ bf8_t packrow(const float* p){
  f4_t a = *(const f4_t*)p;
  f4_t b = *(const f4_t*)(p + 4);
  bf8_t r;
  r[0]=f2bf(a[0]); r[1]=f2bf(a[1]); r[2]=f2bf(a[2]); r[3]=f2bf(a[3]);
  r[4]=f2bf(b[0]); r[5]=f2bf(b[1]); r[6]=f2bf(b[2]); r[7]=f2bf(b[3]);
  return r;
}

struct Par {
  const float *X2, *PMEM;
  const short *WA, *WD, *QWB, *WLOC, *MEMBT, *PJW;
  const float *BSA, *BSD;
  const float *convW, *convb, *vW;
  const float *projb, *gateb;
  const int *mlen;
  float *SBUF, *AC, *DH, *DC, *CTX, *AW, *AWC;
  float *out_mel, *out_gate, *out_align;
};

// att input = [x_t(256) | ctx(t-1)(576) | ac(t-1)(1024)], buffers by parity
__device__ __forceinline__ const float* aptr_att(const Par& p, int rp, int t, int b, int k){
  if (k < PR)      return p.X2 + ((size_t)t*NB + b)*PR + k;
  if (k < PR+ED)   return p.CTX + (size_t)rp*NB*ED + b*ED + (k - PR);
  return p.AC + (size_t)rp*NB*AR + b*AR + (k - PR - ED);
}
// dec input = [ac(t-1)(1024) | ctx(t-1)(576) | dh(t-2)(1024)]
__device__ __forceinline__ const float* aptr_dec(const Par& p, int rp, int wp, int b, int k){
  if (k < AR)      return p.AC + (size_t)rp*NB*AR + b*AR + k;
  if (k < AR+ED)   return p.CTX + (size_t)rp*NB*ED + b*ED + (k - AR);
  return p.DH + (size_t)wp*NB*DR + b*DR + (k - AR - ED);
}

// ---- 8-wave accumulator reduce -> wave 0 (LDS) -----------------------------
__device__ __forceinline__ void reduce8(float* red, f4_t& a0, f4_t& a1, int lane, int wv){
  float* slot = red + (size_t)(wv*64 + lane)*12;
  *(f4_t*)slot       = a0;
  *(f4_t*)(slot + 4) = a1;
  __syncthreads();
  if (wv == 0){
    #pragma unroll
    for (int w = 1; w < 8; ++w){
      const float* s2 = red + (size_t)(w*64 + lane)*12;
      f4_t b0 = *(const f4_t*)s2;
      f4_t b1 = *(const f4_t*)(s2 + 4);
      a0 += b0; a1 += b1;
    }
  }
  __syncthreads();
}

// ============================ per-step kernel 1 =============================
// 256 blocks x 512. dec-gates(t-1)+cell, att-gates(t)+cell, conv+SBUF.
__global__ __launch_bounds__(512) void k_m(Par p, int t, int dec_on, int att_on){
  const int bid = blockIdx.x, tid = threadIdx.x;
  const int lane = tid & 63, wv = tid >> 6;
  const int wp = t & 1, rp = wp ^ 1;
  __shared__ float smem[6400];

  // ---- dec-gates(t-1) + dec-cell ------------------------------------------
  if (dec_on){
    f4_t acc0 = (f4_t){0.f,0.f,0.f,0.f}, acc1 = (f4_t){0.f,0.f,0.f,0.f};
    for (int ks = wv; ks < NKT_D; ks += 8){
      const int kb = ks*32 + ((lane >> 4) << 3);
      const bf8_t a0 = packrow(aptr_dec(p, rp, wp, lane & 15, kb));
      const bf8_t a1 = packrow(aptr_dec(p, rp, wp, 16 + (lane & 15), kb));
      const bf8_t bw = *(const bf8_t*)(p.WD + ((size_t)(bid*NKT_D + ks)*64 + lane)*8);
      acc0 = MFMA(a0, bw, acc0);
      acc1 = MFMA(a1, bw, acc1);
    }
    reduce8(smem, acc0, acc1, lane, wv);
    if (wv == 0){
      const int col = lane & 15, rb2 = (lane >> 4) << 2;
      const int jp = (col & 3)*1024 + bid*4 + (col >> 2);
      const float bs = p.BSD[jp];
      #pragma unroll
      for (int r = 0; r < 4; ++r){
        smem[(rb2 + r)*17 + col]      = acc0[r] + bs;
        smem[(16 + rb2 + r)*17 + col] = acc1[r] + bs;
      }
    }
    __syncthreads();
    if (tid < 128){                    // dec cell: 4 units x 32 batches
      const int b = tid & 31, ul = tid >> 5;
      const int u = bid*4 + ul;
      const float gi = smem[b*17 + ul*4 + 0];
      const float gf = smem[b*17 + ul*4 + 1];
      const float gg = smem[b*17 + ul*4 + 2];
      const float go = smem[b*17 + ul*4 + 3];
      const float c = sigm(gf) * p.DC[(size_t)b*DR + u] + sigm(gi) * tanhf(gg);
      p.DC[(size_t)b*DR + u] = c;
      p.DH[(size_t)rp*NB*DR + b*DR + u] = sigm(go) * tanhf(c);  // dh(t-1)
    }
    __syncthreads();
  }

  if (!att_on) return;

  // ---- att-gates(t) + att-cell --------------------------------------------
  {
    f4_t acc0 = (f4_t){0.f,0.f,0.f,0.f}, acc1 = (f4_t){0.f,0.f,0.f,0.f};
    for (int ks = wv; ks < NKT_A; ks += 8){
      const int kb = ks*32 + ((lane >> 4) << 3);
      const bf8_t a0 = packrow(aptr_att(p, rp, t, lane & 15, kb));
      const bf8_t a1 = packrow(aptr_att(p, rp, t, 16 + (lane & 15), kb));
      const bf8_t bw = *(const bf8_t*)(p.WA + ((size_t)(bid*NKT_A + ks)*64 + lane)*8);
      acc0 = MFMA(a0, bw, acc0);
      acc1 = MFMA(a1, bw, acc1);
    }
    reduce8(smem, acc0, acc1, lane, wv);
    if (wv == 0){
      const int col = lane & 15, rb2 = (lane >> 4) << 2;
      const int jp = (col & 3)*1024 + bid*4 + (col >> 2);
      const float bs = p.BSA[jp];
      #pragma unroll
      for (int r = 0; r < 4; ++r){
        smem[(rb2 + r)*17 + col]      = acc0[r] + bs;
        smem[(16 + rb2 + r)*17 + col] = acc1[r] + bs;
      }
    }
    __syncthreads();
    if (tid < 128){                    // att cell (ref: h overwritten by c)
      const int b = tid & 31, ul = tid >> 5;
      const int u = bid*4 + ul;
      const float gi = smem[b*17 + ul*4 + 0];
      const float gf = smem[b*17 + ul*4 + 1];
      const float gg = smem[b*17 + ul*4 + 2];
      const float c = sigm(gf) * p.AC[(size_t)rp*NB*AR + b*AR + u]
                    + sigm(gi) * tanhf(gg);
      p.AC[(size_t)wp*NB*AR + b*AR + u] = c;
    }
    __syncthreads();
  }

  // ---- location conv + loc-proj -> SBUF, job (b = bid>>3, tc = bid&7) -----
  {
    const int b = bid >> 3, tc = bid & 7, t0 = tc*64;
    float* sAWI = smem + 600;                 // [94][2] interleaved aw/awc
    short* sCwB = (short*)(smem + 800);       // [64][40] bf16
    for (int i = tid; i < 94; i += 512){
      int g = t0 - 15 + i;
      float a = 0.f, w = 0.f;
      if (g >= 0 && g < TI){
        a = p.AW [(size_t)b*TI + g];
        w = p.AWC[(size_t)b*TI + g];
      }
      sAWI[2*i] = a; sAWI[2*i + 1] = w;
    }
    __syncthreads();
    {
      const int wvu = __builtin_amdgcn_readfirstlane(wv);
      const int f0 = wvu * 4;
      float ac4[4];
      #pragma unroll
      for (int ff = 0; ff < 4; ++ff) ac4[ff] = p.convb[f0 + ff];
      for (int k = 0; k < KSz; ++k){
        f2_t a2 = *(const f2_t*)&sAWI[2*(lane + k)];
        #pragma unroll
        for (int ff = 0; ff < 4; ++ff){
          ac4[ff] += a2[0] * p.convW[((f0+ff)*2 + 0)*KSz + k]
                   + a2[1] * p.convW[((f0+ff)*2 + 1)*KSz + k];
        }
      }
      #pragma unroll
      for (int ff = 0; ff < 4; ++ff) sCwB[lane*40 + f0 + ff] = f2bf(ac4[ff]);
    }
    __syncthreads();
    for (int j = wv; j < 32; j += 8){
      const int mt = j >> 3, nt2 = j & 7;
      const bf8_t afr = *(const bf8_t*)(sCwB + (mt*16 + (lane & 15))*40 + ((lane >> 4) << 3));
      const bf8_t bfr = *(const bf8_t*)(p.WLOC + (size_t)(nt2*64 + lane)*8);
      f4_t c = (f4_t){0.f,0.f,0.f,0.f};
      c = MFMA(afr, bfr, c);
      const int tl2 = mt*16 + ((lane >> 4) << 2);
      const int d2  = nt2*16 + (lane & 15);
      #pragma unroll
      for (int r = 0; r < 4; ++r){
        const int tg2 = t0 + tl2 + r;
        p.SBUF[((size_t)b*TI + tg2)*AD + d2] =
          c[r] + p.PMEM[((size_t)b*TI + tg2)*AD + d2];
      }
    }
  }
}

// ============================ per-step kernel 2 =============================
// 32 blocks x 512, block = batch b: q, energies, softmax, ctx, proj(t-1).
__global__ __launch_bounds__(512) void k_s(Par p, int t){
  const int b = blockIdx.x, tid = threadIdx.x;
  const int lane = tid & 63, wv = tid >> 6;
  const int wp = t & 1, rp = wp ^ 1;
  __shared__ float smem[4352];
  float* sAC  = smem;          // 1024
  float* sQ   = smem + 1024;   // 128
  float* red  = smem + 1152;   // 512
  float* sP   = smem + 1664;   // 512
  float* sEN  = smem + 2176;   // 512
  float* sCTX = smem + 2688;   // 576
  float* sDH  = smem + 3264;   // 1024

  // stage: ac(t) [wp], dh(t-1) [rp], ctx(t-1) [rp]
  {
    const float* acp = p.AC + (size_t)wp*NB*AR + (size_t)b*AR;
    const float* dhp = p.DH + (size_t)rp*NB*DR + (size_t)b*DR;
    const float* ctp = p.CTX + (size_t)rp*NB*ED + (size_t)b*ED;
    if (tid < 256)      *(f4_t*)(sAC + tid*4)        = *(const f4_t*)(acp + tid*4);
    else                *(f4_t*)(sDH + (tid-256)*4)  = *(const f4_t*)(dhp + (tid-256)*4);
    if (tid < 144)      *(f4_t*)(sCTX + tid*4)       = *(const f4_t*)(ctp + tid*4);
  }
  __syncthreads();

  // q[128] = qW @ ac   (QWB plain [128][1024] bf16, L2-hot)
  for (int rr = 0; rr < 16; ++rr){
    const int d = wv*16 + rr;
    const short* qr = p.QWB + (size_t)d*AR;
    float s = 0.f;
    #pragma unroll
    for (int i = 0; i < 8; ++i){
      const unsigned pk = *(const unsigned*)(qr + i*128 + lane*2);
      s += bf2f((short)(pk & 0xffff)) * sAC[i*128 + lane*2]
         + bf2f((short)(pk >> 16))    * sAC[i*128 + lane*2 + 1];
    }
    #pragma unroll
    for (int d2 = 32; d2 > 0; d2 >>= 1) s += __shfl_down(s, d2);
    if (lane == 0) sQ[d] = s;
  }
  __syncthreads();

  // energies -> sEN  (8 threads per t, 16 d each)
  {
    const int ml = p.mlen[b];
    const int tl = tid >> 3, dq = tid & 7;
    for (int tt = 0; tt < 8; ++tt){
      const int tg = tt*64 + tl;
      const float* sb = p.SBUF + ((size_t)b*TI + tg)*AD;
      float s = 0.f;
      #pragma unroll
      for (int j = 0; j < 16; ++j){
        const int d = dq*16 + j;
        s += p.vW[d] * tanhf(sQ[d] + sb[d]);
      }
      s += __shfl_down(s, 1);
      s += __shfl_down(s, 2);
      s += __shfl_down(s, 4);
      if (dq == 0) sEN[tg] = (tg < ml) ? s : -1e30f;
    }
  }
  __syncthreads();

  // softmax over 512
  {
    const float e = sEN[tid];
    red[tid] = e; __syncthreads();
    for (int s2 = 256; s2 > 0; s2 >>= 1){
      if (tid < s2) red[tid] = fmaxf(red[tid], red[tid + s2]);
      __syncthreads();
    }
    const float M = red[0]; __syncthreads();
    const float x = __expf(e - M);
    red[tid] = x; __syncthreads();
    for (int s2 = 256; s2 > 0; s2 >>= 1){
      if (tid < s2) red[tid] += red[tid + s2];
      __syncthreads();
    }
    const float Z = red[0]; __syncthreads();
    const float pv = x / Z;
    sP[tid] = pv;
    p.AW [(size_t)b*TI + tid] = pv;
    p.AWC[(size_t)b*TI + tid] += pv;
    p.out_align[((size_t)b*TO + t)*TI + tid] = pv;
  }
  __syncthreads();

  // ctx(t) = aw @ memory[b]  (MEMBT [b][e][t] bf16) -> CTX[wp]
  for (int ii = 0; ii < 72; ++ii){
    const int e2 = wv*72 + ii;
    const short* row = p.MEMBT + ((size_t)b*ED + e2)*TI;
    float a2 = 0.f;
    #pragma unroll
    for (int c = 0; c < 8; ++c)
      a2 += sP[c*64 + lane] * bf2f(row[c*64 + lane]);
    #pragma unroll
    for (int d = 32; d > 0; d >>= 1) a2 += __shfl_down(a2, d);
    if (lane == 0)
      p.CTX[(size_t)wp*NB*ED + b*ED + e2] = a2;
  }

  // proj(t-1): mel/gate from [dh(t-1) | ctx(t-1)]
  if (t > 0){
    const int tprev = t - 1;
    for (int o = wv; o < 81; o += 8){
      const short* wr = p.PJW + (size_t)o*1600;
      float s = 0.f;
      for (int k = lane; k < 1600; k += 64){
        float in = (k < DR) ? sDH[k] : sCTX[k - DR];
        s += in * bf2f(wr[k]);
      }
      #pragma unroll
      for (int d = 32; d > 0; d >>= 1) s += __shfl_down(s, d);
      if (lane == 0){
        if (o < 80) p.out_mel[((size_t)b*NM + o)*TO + tprev] = s + p.projb[o];
        else        p.out_gate[(size_t)b*TO + tprev] = s + p.gateb[0];
      }
    }
  }
}

// final proj for t = 399 (reads DH[1], CTX[1])
__global__ __launch_bounds__(512) void k_proj(Par p){
  const int b = blockIdx.x, tid = threadIdx.x;
  const int lane = tid & 63, wv = tid >> 6;
  __shared__ float smem[1664];
  float* sDH  = smem;
  float* sCTX = smem + 1088;
  {
    const float* dhp = p.DH + (size_t)1*NB*DR + (size_t)b*DR;
    const float* ctp = p.CTX + (size_t)1*NB*ED + (size_t)b*ED;
    if (tid < 256) *(f4_t*)(sDH + tid*4) = *(const f4_t*)(dhp + tid*4);
    else if (tid < 400) *(f4_t*)(sCTX + (tid-256)*4) = *(const f4_t*)(ctp + (tid-256)*4);
  }
  __syncthreads();
  for (int o = wv; o < 81; o += 8){
    const short* wr = p.PJW + (size_t)o*1600;
    float s = 0.f;
    for (int k = lane; k < 1600; k += 64){
      float in = (k < DR) ? sDH[k] : sCTX[k - DR];
      s += in * bf2f(wr[k]);
    }
    #pragma unroll
    for (int d = 32; d > 0; d >>= 1) s += __shfl_down(s, d);
    if (lane == 0){
      if (o < 80) p.out_mel[((size_t)b*NM + o)*TO + (TO-1)] = s + p.projb[o];
      else        p.out_gate[(size_t)b*TO + (TO-1)] = s + p.gateb[0];
    }
  }
}

// ============================ setup kernels =================================
__global__ __launch_bounds__(256) void k_init(float* z, int nz,
                                              float* bsa, const float* a1, const float* a2,
                                              float* bsd, const float* d1, const float* d2){
  const int idx = blockIdx.x*256 + threadIdx.x, st = gridDim.x*256;
  for (int i = idx; i < nz; i += st) z[i] = 0.f;
  for (int i = idx; i < 4096; i += st){ bsa[i] = a1[i] + a2[i]; bsd[i] = d1[i] + d2[i]; }
}

__global__ __launch_bounds__(256) void k_prenet1(const float* di, const float* W1, float* X1){
  const int t = blockIdx.x, tid = threadIdx.x;
  __shared__ float sdi[NB*NM];
  for (int i = tid; i < NB*NM; i += 256){
    const int b = i / NM, k = i - b*NM;
    sdi[i] = (t == 0) ? 0.f : di[((size_t)b*TO + (t-1))*NM + k];
  }
  __syncthreads();
  float acc[NB];
  #pragma unroll
  for (int b = 0; b < NB; ++b) acc[b] = 0.f;
  const int j = tid;
  for (int k = 0; k < NM; ++k){
    const float w = W1[j*NM + k];
    #pragma unroll
    for (int b = 0; b < NB; ++b) acc[b] += sdi[b*NM + k] * w;
  }
  for (int b = 0; b < NB; ++b)
    X1[((size_t)t*NB + b)*PR + j] = fmaxf(acc[b], 0.f);
}

__global__ __launch_bounds__(256) void k_prenet2(const float* X1, const float* W2, float* X2){
  const int t = blockIdx.x, tid = threadIdx.x;
  __shared__ float sx[NB*PR];
  for (int i = tid; i < NB*PR; i += 256) sx[i] = X1[(size_t)t*NB*PR + i];
  __syncthreads();
  float acc[NB];
  #pragma unroll
  for (int b = 0; b < NB; ++b) acc[b] = 0.f;
  const int j = tid;
  for (int k = 0; k < PR; ++k){
    const float w = W2[j*PR + k];
    #pragma unroll
    for (int b = 0; b < NB; ++b) acc[b] += sx[b*PR + k] * w;
  }
  for (int b = 0; b < NB; ++b)
    X2[((size_t)t*NB + b)*PR + j] = fmaxf(acc[b], 0.f);
}

__global__ __launch_bounds__(256) void k_pmem(const float* mem, const float* memW, float* pm){
  const int b = blockIdx.x >> 3, tc = blockIdx.x & 7, tid = threadIdx.x;
  __shared__ float sW[64*AD];
  __shared__ float sM[64*65];
  const int tl = tid >> 2, dq = tid & 3;
  float acc[32];
  #pragma unroll
  for (int i = 0; i < 32; ++i) acc[i] = 0.f;
  for (int kc = 0; kc < 9; ++kc){
    __syncthreads();
    for (int i = tid; i < 64*AD; i += 256){
      const int d = i >> 6, kl = i & 63;
      sW[kl*AD + ((d + kl) & 127)] = memW[(size_t)d*ED + kc*64 + kl];
    }
    for (int i = tid; i < 64*64; i += 256){
      const int tt = i >> 6, kl = i & 63;
      sM[tt*65 + kl] = mem[((size_t)b*TI + tc*64 + tt)*ED + kc*64 + kl];
    }
    __syncthreads();
    for (int kl = 0; kl < 64; ++kl){
      const float mv = sM[tl*65 + kl];
      #pragma unroll
      for (int d2 = 0; d2 < 32; ++d2)
        acc[d2] += mv * sW[kl*AD + ((dq*32 + d2 + kl) & 127)];
    }
  }
  for (int d2 = 0; d2 < 32; ++d2)
    pm[((size_t)b*TI + tc*64 + tl)*AD + dq*32 + d2] = acc[d2];
}

__global__ __launch_bounds__(256) void k_membt(const float* mem, short* mt){
  const int b = blockIdx.x / 36, ec = blockIdx.x % 36;
  __shared__ float sT[64*17];
  for (int tc = 0; tc < 8; ++tc){
    __syncthreads();
    for (int i = threadIdx.x; i < 64*16; i += 256){
      const int tt = i >> 4, e = i & 15;
      sT[tt*17 + e] = mem[((size_t)b*TI + tc*64 + tt)*ED + ec*16 + e];
    }
    __syncthreads();
    for (int i = threadIdx.x; i < 16*64; i += 256){
      const int e = i >> 6, tt = i & 63;
      mt[((size_t)b*ED + ec*16 + e)*TI + tc*64 + tt] = f2bf(sT[tt*17 + e]);
    }
  }
}

__global__ __launch_bounds__(64) void k_swz_gate(const float* Wih, const float* Whh,
                                                 short* dst, int split, int nkt){
  const int bidx = blockIdx.x;
  const int nt = bidx / nkt, kt = bidx - nt*nkt;
  const int lane = threadIdx.x;
  const int nl = lane & 15;
  const int jp = (nl & 3)*1024 + nt*4 + (nl >> 2);
  const int k0 = kt*32 + ((lane >> 4) << 3);
  bf8_t v;
  #pragma unroll
  for (int jj = 0; jj < 8; ++jj){
    const int k = k0 + jj;
    const float f = (k < split) ? Wih[(size_t)jp*split + k]
                                : Whh[(size_t)jp*1024 + (k - split)];
    v[jj] = f2bf(f);
  }
  *(bf8_t*)(dst + (size_t)bidx*512 + lane*8) = v;
}

__global__ __launch_bounds__(256) void k_qwb(const float* qW, short* dst){
  const int idx = blockIdx.x*256 + threadIdx.x, st = gridDim.x*256;
  for (int i = idx; i < AD*AR; i += st) dst[i] = f2bf(qW[i]);
}

__global__ __launch_bounds__(64) void k_swz_loc(const float* locW, short* dst){
  const int nt = blockIdx.x;
  const int lane = threadIdx.x;
  const int d = nt*16 + (lane & 15);
  const int f0 = (lane >> 4) << 3;
  bf8_t v;
  #pragma unroll
  for (int jj = 0; jj < 8; ++jj) v[jj] = f2bf(locW[d*NFl + f0 + jj]);
  *(bf8_t*)(dst + (size_t)(nt*64 + lane)*8) = v;
}

__global__ __launch_bounds__(256) void k_swz_proj(const float* projW, const float* gateW,
                                                  short* dst){
  const int o = blockIdx.x;
  const float* src = (o < 80) ? (projW + (size_t)o*1600) : gateW;
  for (int k = threadIdx.x; k < 1600; k += 256)
    dst[(size_t)o*1600 + k] = f2bf(src[k]);
}

// ============================== launch ======================================
extern "C" void kernel_launch(void* const* d_in, const int* in_sizes, int n_in,
                              void* d_out, int out_size, void* d_ws, size_t ws_size,
                              hipStream_t stream){
  const float* mem    = (const float*)d_in[0];
  const float* dec_in = (const float*)d_in[1];
  const float* pW1    = (const float*)d_in[2];
  const float* pW2    = (const float*)d_in[3];
  const float* aWih   = (const float*)d_in[4];
  const float* aWhh   = (const float*)d_in[5];
  const float* aBih   = (const float*)d_in[6];
  const float* aBhh   = (const float*)d_in[7];
  const float* qW     = (const float*)d_in[8];
  const float* memW   = (const float*)d_in[9];
  const float* convW  = (const float*)d_in[10];
  const float* convb  = (const float*)d_in[11];
  const float* locW   = (const float*)d_in[12];
  const float* vW     = (const float*)d_in[13];
  const float* dWih   = (const float*)d_in[14];
  const float* dWhh   = (const float*)d_in[15];
  const float* dBih   = (const float*)d_in[16];
  const float* dBhh   = (const float*)d_in[17];
  const float* projW  = (const float*)d_in[18];
  const float* projb  = (const float*)d_in[19];
  const float* gateW  = (const float*)d_in[20];
  const float* gateb  = (const float*)d_in[21];
  const int*   mlen   = (const int*)d_in[22];
  (void)in_sizes; (void)n_in; (void)out_size; (void)ws_size;

  char* basep = (char*)d_ws;
  size_t off = 0;
  auto carve = [&](size_t bytes) -> char* {
    char* r = basep + off;
    off = (off + bytes + 255) & ~(size_t)255;
    return r;
  };
  short* WA    = (short*)carve((size_t)4096*KA*2);
  short* WD    = (short*)carve((size_t)4096*KD*2);
  short* QWB   = (short*)carve((size_t)AD*AR*2);
  short* WLOC  = (short*)carve((size_t)AD*NFl*2);
  short* MEMBT = (short*)carve((size_t)NB*TI*ED*2);
  short* PJW   = (short*)carve((size_t)81*1600*2);
  float* X1    = (float*)carve((size_t)TO*NB*PR*4);
  float* X2    = (float*)carve((size_t)TO*NB*PR*4);
  float* PMEM  = (float*)carve((size_t)NB*TI*AD*4);
  float* SBUF  = (float*)carve((size_t)NB*TI*AD*4);
  float* BSA   = (float*)carve((size_t)4096*4);
  float* BSD   = (float*)carve((size_t)4096*4);
  // ---- zero-span begins here ----
  float* AC    = (float*)carve((size_t)2*NB*AR*4);
  float* DH    = (float*)carve((size_t)2*NB*DR*4);
  float* DC    = (float*)carve((size_t)NB*DR*4);
  float* CTX   = (float*)carve((size_t)2*NB*ED*4);
  float* AW    = (float*)carve((size_t)NB*TI*4);
  float* AWC   = (float*)carve((size_t)NB*TI*4);
  char*  zend  = basep + off;
  const int nz = (int)((zend - (char*)AC) / 4);

  float* out_mel   = (float*)d_out;
  float* out_gate  = out_mel + (size_t)NB*NM*TO;
  float* out_align = out_gate + (size_t)NB*TO;

  k_init   <<<dim3(512), dim3(256), 0, stream>>>(AC, nz, BSA, aBih, aBhh, BSD, dBih, dBhh);
  k_prenet1<<<dim3(TO),  dim3(256), 0, stream>>>(dec_in, pW1, X1);
  k_prenet2<<<dim3(TO),  dim3(256), 0, stream>>>(X1, pW2, X2);
  k_pmem   <<<dim3(256), dim3(256), 0, stream>>>(mem, memW, PMEM);
  k_membt  <<<dim3(NB*36), dim3(256), 0, stream>>>(mem, MEMBT);
  k_swz_gate<<<dim3(256*NKT_A), dim3(64), 0, stream>>>(aWih, aWhh, WA, 832, NKT_A);
  k_swz_gate<<<dim3(256*NKT_D), dim3(64), 0, stream>>>(dWih, dWhh, WD, 1600, NKT_D);
  k_qwb    <<<dim3(128), dim3(256), 0, stream>>>(qW, QWB);
  k_swz_loc<<<dim3(8),   dim3(64), 0, stream>>>(locW, WLOC);
  k_swz_proj<<<dim3(81), dim3(256), 0, stream>>>(projW, gateW, PJW);

  Par p;
  p.X2 = X2; p.PMEM = PMEM;
  p.WA = WA; p.WD = WD; p.QWB = QWB; p.WLOC = WLOC; p.MEMBT = MEMBT; p.PJW = PJW;
  p.BSA = BSA; p.BSD = BSD;
  p.convW = convW; p.convb = convb; p.vW = vW;
  p.projb = projb; p.gateb = gateb;
  p.mlen = mlen;
  p.SBUF = SBUF;
  p.AC = AC; p.DH = DH; p.DC = DC; p.CTX = CTX;
  p.AW = AW; p.AWC = AWC;
  p.out_mel = out_mel; p.out_gate = out_gate; p.out_align = out_align;

  for (int t = 0; t < TO; ++t){
    k_m<<<dim3(256), dim3(512), 0, stream>>>(p, t, (t > 0) ? 1 : 0, 1);
    k_s<<<dim3(NB),  dim3(512), 0, stream>>>(p, t);
  }
  k_m   <<<dim3(256), dim3(512), 0, stream>>>(p, TO, 1, 0);
  k_proj<<<dim3(NB),  dim3(512), 0, stream>>>(p);
}